// Round 6
// baseline (75.132 us; speedup 1.0000x reference)
//
#include <hip/hip_runtime.h>

typedef float f32x4 __attribute__((ext_vector_type(4)));
typedef short s16x8 __attribute__((ext_vector_type(8)));

#define M_DIM 32
#define N_DIM 8192
#define K_DIM 8192
#define NBLK (K_DIM / 16)   // 512 fp4 blocks along K
#define KSPLIT 2
#define BLK_K 4096          // k-range per block
#define TILE_K 256          // k per staged tile
#define NTILES (BLK_K / TILE_K)       // 16
#define ROW_STRIDE 1040     // LDS bytes per staged row (1024 + 16 pad -> 2-way max)
#define SLOT_BYTES (16 * ROW_STRIDE)  // 16640
// LDS: 2 slots = 33280 B -> exactly 4 blocks/CU (133 KB), 32 waves/CU

// float -> bf16 bits, round-to-nearest-even (data has no NaNs)
__device__ inline unsigned short f2bf(float f) {
    unsigned int u = __float_as_uint(f);
    u = (u + 0x7FFFu + ((u >> 16) & 1u)) >> 16;
    return (unsigned short)u;
}

// Nearest FP4 (e2m1); ties at the boundary go DOWN (searchsorted side='left').
__device__ inline float round_fp4(float x) {
    float a = fabsf(x);
    float g;
    if (a > 2.5f)        g = (a > 5.0f) ? 6.0f : ((a > 3.5f) ? 4.0f : 3.0f);
    else if (a > 1.25f)  g = (a > 1.75f) ? 2.0f : 1.5f;
    else                 g = (a > 0.75f) ? 1.0f : ((a > 0.25f) ? 0.5f : 0.0f);
    return copysignf(g, x);
}

// Saturating RNE cast to float8_e4m3fn and back (v >= 0 here).
__device__ inline float cast_e4m3(float v) {
    v = fminf(v, 448.0f);
    if (v < 0.015625f) {                       // subnormal range, step 2^-9
        return rintf(v * 512.0f) * (1.0f / 512.0f);
    }
    int e; float m = frexpf(v, &e);            // m in [0.5, 1)
    return ldexpf(rintf(m * 16.0f) * 0.0625f, e);
}

__device__ __forceinline__ void async_copy16(const void* g, void* l) {
    __builtin_amdgcn_global_load_lds((const __attribute__((address_space(1))) void*)g,
                                     (__attribute__((address_space(3))) void*)l, 16, 0, 0);
}

// ---------------------------------------------------------------------------
// out[m][n] = bias[n]  (runs every call; gemm atomics accumulate onto it)
// ---------------------------------------------------------------------------
__global__ void init_out(const float* __restrict__ bias, float* __restrict__ out) {
    int i = blockIdx.x * blockDim.x + threadIdx.x;   // 65536 threads, 4 floats each
    f32x4 b = *(const f32x4*)(bias + ((i * 4) & (N_DIM - 1)));
    *(f32x4*)(out + (size_t)i * 4) = b;
}

// ---------------------------------------------------------------------------
// Phase 1: NVFP4 fake-quant of x, packed into MFMA B-fragment layout (bf16).
// Short index: kstep*1024 + t*512 + lane*8 + j  holds
//   x_dq[m = t*16 + (lane&15)][k = kstep*32 + (lane>>4)*8 + j]
// ---------------------------------------------------------------------------
__global__ void quant_pack_x(const float* __restrict__ x,
                             const float* __restrict__ input_scale,
                             unsigned short* __restrict__ xpack) {
    int tid = blockIdx.x * blockDim.x + threadIdx.x;   // 16384 threads
    int m = tid >> 9;          // row 0..31
    int b = tid & 511;         // 16-block along K
    const float is = input_scale[0];

    const float* xp = x + (size_t)m * K_DIM + b * 16;
    f32x4 l0 = *(const f32x4*)(xp);
    f32x4 l1 = *(const f32x4*)(xp + 4);
    f32x4 l2 = *(const f32x4*)(xp + 8);
    f32x4 l3 = *(const f32x4*)(xp + 12);
    float v[16];
    #pragma unroll
    for (int i = 0; i < 4; ++i) { v[i]=l0[i]; v[4+i]=l1[i]; v[8+i]=l2[i]; v[12+i]=l3[i]; }

    float amax = 0.f;
    #pragma unroll
    for (int i = 0; i < 16; ++i) amax = fmaxf(amax, fabsf(v[i]));

    float sf = cast_e4m3(amax / 6.0f / is);
    float scale = sf * is;

    int kstep = b >> 1;
    int t = m >> 4;
    int mrow = m & 15;
    unsigned short* base = xpack + (size_t)kstep * 1024 + t * 512;
    #pragma unroll
    for (int i = 0; i < 16; ++i) {
        float q = 0.f;
        if (scale > 0.f) q = round_fp4(v[i] / scale) * scale;
        int g = ((b & 1) << 1) + (i >> 3);   // k-group 0..3 within kstep
        int lane = g * 16 + mrow;
        int j = i & 7;
        base[lane * 8 + j] = f2bf(q);
    }
}

// ---------------------------------------------------------------------------
// Phase 2: split-K GEMM with CONTIGUOUS W staging.
// Grid = (512 n-tiles) x (2 k-splits) = 1024 blocks x 512 thr
//   -> 4 blocks/CU x 8 waves = 32 waves/CU, one exact residency pass.
// Per tile (16 rows x 256 k = 16KB): each wave stages 2 rows as 1KB-contiguous
// global_load_lds (copy-like DRAM pattern). m97-style double buffer, one
// __syncthreads per tile (compiler drains vmcnt before s_barrier).
// Each wave computes k-step w of every tile (2 MFMAs/tile).
// ---------------------------------------------------------------------------
__global__ __launch_bounds__(512, 8) void gemm_kernel(
    const float* __restrict__ W,
    const float* __restrict__ wscale,
    const float* __restrict__ ws2p,
    const unsigned short* __restrict__ xpack,
    float* __restrict__ out)
{
    __shared__ __align__(16) unsigned char lds[2 * SLOT_BYTES];  // 33280 B

    const int wave = threadIdx.x >> 6;   // 0..7
    const int lane = threadIdx.x & 63;
    const int lrow = lane & 15;          // W row (n) sub-index
    const int lgrp = lane >> 4;          // k-group 0..3
    const int n0 = blockIdx.x * 16;
    const int kb = blockIdx.y;           // 0..1
    const float ws2 = ws2p[0];

    // staging sources: wave stages rows 2w, 2w+1; 1KB contiguous per instr
    const float* wsrc0 = W + (size_t)(n0 + 2 * wave)     * K_DIM + kb * BLK_K + lane * 4;
    const float* wsrc1 = W + (size_t)(n0 + 2 * wave + 1) * K_DIM + kb * BLK_K + lane * 4;

    auto stage = [&](int t) {
        unsigned char* slot = lds + (t & 1) * SLOT_BYTES;
        async_copy16(wsrc0 + t * TILE_K, slot + (2 * wave)     * ROW_STRIDE);
        async_copy16(wsrc1 + t * TILE_K, slot + (2 * wave + 1) * ROW_STRIDE);
    };

    // per-wave compute sources (k-step S = kb*128 + t*8 + wave)
    const int S0 = kb * 128 + wave;                       // t=0
    const unsigned short* xcur = xpack + (size_t)S0 * 1024 + lane * 8;
    const float* scur = wscale + (size_t)(n0 + lrow) * NBLK + S0 * 2 + (lgrp >> 1);
    const int aoff = wave * 128 + lgrp * 32;              // byte offset in row

    f32x4 acc0 = {0,0,0,0}, acc1 = {0,0,0,0};

    stage(0);
    __syncthreads();

    #pragma unroll 2
    for (int t = 0; t < NTILES; ++t) {
        if (t + 1 < NTILES) stage(t + 1);
        const unsigned char* slot = lds + (t & 1) * SLOT_BYTES;
        f32x4 a0 = *(const f32x4*)(slot + lrow * ROW_STRIDE + aoff);
        f32x4 a1 = *(const f32x4*)(slot + lrow * ROW_STRIDE + aoff + 16);
        s16x8 b0 = *(const s16x8*)(xcur);
        s16x8 b1 = *(const s16x8*)(xcur + 512);
        float sc = *scur * ws2;
        s16x8 af;
        #pragma unroll
        for (int j = 0; j < 4; ++j) {
            af[j]     = (short)f2bf(a0[j] * sc);
            af[4 + j] = (short)f2bf(a1[j] * sc);
        }
        acc0 = __builtin_amdgcn_mfma_f32_16x16x32_bf16(af, b0, acc0, 0, 0, 0);
        acc1 = __builtin_amdgcn_mfma_f32_16x16x32_bf16(af, b1, acc1, 0, 0, 0);
        xcur += 8 * 1024;        // next tile: S += 8
        scur += 16;
        __syncthreads();         // stage(t+1) drained; all waves done reading t
    }

    // ---- intra-block reduce over the 8 waves' disjoint k partials ----
    float* red = (float*)lds;            // [8][512] = 16KB, fits in staging LDS
    #pragma unroll
    for (int r = 0; r < 4; ++r) {
        red[wave * 512 + lane * 8 + r]     = acc0[r];
        red[wave * 512 + lane * 8 + 4 + r] = acc1[r];
    }
    __syncthreads();

    // 512 threads -> 512 outputs; D layout: col(lane&15)=m, row((lane>>4)*4+r)=n
    {
        int j = threadIdx.x;
        float v = 0.f;
        #pragma unroll
        for (int w = 0; w < 8; ++w) v += red[w * 512 + j];
        int l = j >> 3, t = (j >> 2) & 1, r = j & 3;
        int m = t * 16 + (l & 15);
        int n = n0 + ((l >> 4) << 2) + r;
        atomicAdd(out + (size_t)m * N_DIM + n, v);
    }
}

extern "C" void kernel_launch(void* const* d_in, const int* in_sizes, int n_in,
                              void* d_out, int out_size, void* d_ws, size_t ws_size,
                              hipStream_t stream) {
    const float* x           = (const float*)d_in[0];
    const float* weight_fp4  = (const float*)d_in[1];
    const float* bias        = (const float*)d_in[2];
    const float* input_scale = (const float*)d_in[3];
    const float* wscale      = (const float*)d_in[4];
    const float* ws2         = (const float*)d_in[5];
    float* out = (float*)d_out;
    unsigned short* xpack = (unsigned short*)d_ws;   // 512 KB

    init_out<<<256, 256, 0, stream>>>(bias, out);
    quant_pack_x<<<64, 256, 0, stream>>>(x, input_scale, xpack);
    gemm_kernel<<<dim3(512, KSPLIT), 512, 0, stream>>>(weight_fp4, wscale, ws2, xpack, out);
}

// Round 7
// 67.492 us; speedup vs baseline: 1.1132x; 1.1132x over previous
//
#include <hip/hip_runtime.h>

typedef float f32x4 __attribute__((ext_vector_type(4)));
typedef short s16x8 __attribute__((ext_vector_type(8)));

#define M_DIM 32
#define N_DIM 8192
#define K_DIM 8192
#define NBLK (K_DIM / 16)   // 512 fp4 blocks along K
#define KSPLIT 4
#define WSTEPS 16           // MFMA k-steps per wave (512 k / 32)
#define SCL_LD 129          // padded LDS stride for scales

// float -> bf16 bits, round-to-nearest-even (data has no NaNs)
__device__ inline unsigned short f2bf(float f) {
    unsigned int u = __float_as_uint(f);
    u = (u + 0x7FFFu + ((u >> 16) & 1u)) >> 16;
    return (unsigned short)u;
}

// Nearest FP4 (e2m1); ties at the boundary go DOWN (searchsorted side='left').
__device__ inline float round_fp4(float x) {
    float a = fabsf(x);
    float g;
    if (a > 2.5f)        g = (a > 5.0f) ? 6.0f : ((a > 3.5f) ? 4.0f : 3.0f);
    else if (a > 1.25f)  g = (a > 1.75f) ? 2.0f : 1.5f;
    else                 g = (a > 0.75f) ? 1.0f : ((a > 0.25f) ? 0.5f : 0.0f);
    return copysignf(g, x);
}

// Saturating RNE cast to float8_e4m3fn and back (v >= 0 here).
__device__ inline float cast_e4m3(float v) {
    v = fminf(v, 448.0f);
    if (v < 0.015625f) {                       // subnormal range, step 2^-9
        return rintf(v * 512.0f) * (1.0f / 512.0f);
    }
    int e; float m = frexpf(v, &e);            // m in [0.5, 1)
    return ldexpf(rintf(m * 16.0f) * 0.0625f, e);
}

// ---------------------------------------------------------------------------
// Fused prep: blocks 0..63  -> NVFP4 fake-quant of x into xpack (B-frag layout)
//             blocks 64..319 -> out[m][n] = bias[n]
// ---------------------------------------------------------------------------
__global__ void prep_kernel(const float* __restrict__ x,
                            const float* __restrict__ input_scale,
                            const float* __restrict__ bias,
                            unsigned short* __restrict__ xpack,
                            float* __restrict__ out) {
    if (blockIdx.x >= 64) {
        int i = (blockIdx.x - 64) * blockDim.x + threadIdx.x;  // 65536 thr * 4 f
        f32x4 b = *(const f32x4*)(bias + ((i * 4) & (N_DIM - 1)));
        *(f32x4*)(out + (size_t)i * 4) = b;
        return;
    }
    int tid = blockIdx.x * blockDim.x + threadIdx.x;   // 16384 threads
    int m = tid >> 9;          // row 0..31
    int b = tid & 511;         // 16-block along K
    const float is = input_scale[0];

    const float* xp = x + (size_t)m * K_DIM + b * 16;
    f32x4 l0 = *(const f32x4*)(xp);
    f32x4 l1 = *(const f32x4*)(xp + 4);
    f32x4 l2 = *(const f32x4*)(xp + 8);
    f32x4 l3 = *(const f32x4*)(xp + 12);
    float v[16];
    #pragma unroll
    for (int i = 0; i < 4; ++i) { v[i]=l0[i]; v[4+i]=l1[i]; v[8+i]=l2[i]; v[12+i]=l3[i]; }

    float amax = 0.f;
    #pragma unroll
    for (int i = 0; i < 16; ++i) amax = fmaxf(amax, fabsf(v[i]));

    float sf = cast_e4m3(amax / 6.0f / is);
    float scale = sf * is;

    int kstep = b >> 1;
    int t = m >> 4;
    int mrow = m & 15;
    unsigned short* base = xpack + (size_t)kstep * 1024 + t * 512;
    #pragma unroll
    for (int i = 0; i < 16; ++i) {
        float q = 0.f;
        if (scale > 0.f) q = round_fp4(v[i] / scale) * scale;
        int g = ((b & 1) << 1) + (i >> 3);   // k-group 0..3 within kstep
        int lane = g * 16 + mrow;
        int j = i & 7;
        base[lane * 8 + j] = f2bf(q);
    }
}

// ---------------------------------------------------------------------------
// Phase 2: streaming split-K GEMM (r5 structure) + bijective XCD swizzle.
// 1-D grid 2048, 256 thr (4 waves) -> 8 blocks/CU, 32 waves/CU.
// Swizzle: xcd = bid&7 owns n-rows [xcd*1024, +1024) x full K -> each XCD's
// L2/fabric port streams one contiguous 32 MB W band; ksplit-siblings of a
// tile are adjacent. Each wave: 16 rows x 512 k, depth-2 VGPR pipeline,
// scales preloaded to LDS, intra-block LDS reduce, atomicAdd epilogue.
// ---------------------------------------------------------------------------
__global__ __launch_bounds__(256, 8) void gemm_kernel(
    const float* __restrict__ W,
    const float* __restrict__ wscale,
    const float* __restrict__ ws2p,
    const unsigned short* __restrict__ xpack,
    float* __restrict__ out)
{
    __shared__ float shm[16 * SCL_LD];   // 8256 B; scales, then reduce buffer

    // ---- XCD-bijective swizzle (2048 = 8 XCDs x 256 blocks) ----
    const int bid   = blockIdx.x;
    const int xcd   = bid & 7;
    const int local = bid >> 3;                 // 0..255 within XCD
    const int ntile = xcd * 64 + (local >> 2);  // 0..511
    const int kb    = local & 3;                // 0..3

    const int wave = threadIdx.x >> 6;   // 0..3 : k sub-split within block
    const int lane = threadIdx.x & 63;
    const int lrow = lane & 15;          // W row (n) sub-index
    const int lgrp = lane >> 4;          // k-group 0..3
    const int n0 = ntile * 16;
    const float ws2 = ws2p[0];

    // ---- preload scales * ws2: rows n0..n0+15, scale-cols kb*128..+128 ----
    {
        int t = threadIdx.x;
        int row = t >> 4;
        int c0 = (t & 15) * 8;
        const float* s = wscale + (size_t)(n0 + row) * NBLK + kb * 128 + c0;
        #pragma unroll
        for (int j = 0; j < 8; ++j)
            shm[row * SCL_LD + c0 + j] = s[j] * ws2;
    }
    __syncthreads();

    const int kofs = kb * 2048 + wave * 512;          // this wave's k start
    const float* wcur = W + (size_t)(n0 + lrow) * K_DIM + kofs + lgrp * 8;
    const unsigned short* xcur = xpack + (size_t)(kofs >> 5) * 1024 + lane * 8;
    const float* sbase = shm + lrow * SCL_LD + wave * 32 + (lgrp >> 1);

    f32x4 acc0 = {0,0,0,0}, acc1 = {0,0,0,0};

    // depth-2 software pipeline (compiler inserts the vmcnt waits)
    f32x4 a0 = *(const f32x4*)(wcur);
    f32x4 a1 = *(const f32x4*)(wcur + 4);
    s16x8 b0 = *(const s16x8*)(xcur);
    s16x8 b1 = *(const s16x8*)(xcur + 512);

    #pragma unroll
    for (int s = 0; s < WSTEPS; ++s) {
        f32x4 na0, na1; s16x8 nb0, nb1;
        if (s + 1 < WSTEPS) {             // static with full unroll
            na0 = *(const f32x4*)(wcur + 32);
            na1 = *(const f32x4*)(wcur + 36);
            nb0 = *(const s16x8*)(xcur + 1024);
            nb1 = *(const s16x8*)(xcur + 1536);
        }
        float sc = sbase[s * 2];
        s16x8 af;
        #pragma unroll
        for (int j = 0; j < 4; ++j) {
            af[j]     = (short)f2bf(a0[j] * sc);
            af[4 + j] = (short)f2bf(a1[j] * sc);
        }
        acc0 = __builtin_amdgcn_mfma_f32_16x16x32_bf16(af, b0, acc0, 0, 0, 0);
        acc1 = __builtin_amdgcn_mfma_f32_16x16x32_bf16(af, b1, acc1, 0, 0, 0);
        a0 = na0; a1 = na1; b0 = nb0; b1 = nb1;
        wcur += 32;
        xcur += 1024;
    }

    // ---- intra-block reduce over the 4 k-split waves ----
    __syncthreads();                      // scale reads done; reuse shm
    float* red = shm;                     // [4][512]
    #pragma unroll
    for (int r = 0; r < 4; ++r) {
        red[wave * 512 + lane * 8 + r]     = acc0[r];
        red[wave * 512 + lane * 8 + 4 + r] = acc1[r];
    }
    __syncthreads();

    // 256 threads -> 512 outputs; D layout: col(lane&15)=m, row((lane>>4)*4+r)=n
    #pragma unroll
    for (int h = 0; h < 2; ++h) {
        int j = threadIdx.x + h * 256;
        float v = red[j] + red[512 + j] + red[1024 + j] + red[1536 + j];
        int l = j >> 3, t = (j >> 2) & 1, r = j & 3;
        int m = t * 16 + (l & 15);
        int n = n0 + ((l >> 4) << 2) + r;
        atomicAdd(out + (size_t)m * N_DIM + n, v);
    }
}

extern "C" void kernel_launch(void* const* d_in, const int* in_sizes, int n_in,
                              void* d_out, int out_size, void* d_ws, size_t ws_size,
                              hipStream_t stream) {
    const float* x           = (const float*)d_in[0];
    const float* weight_fp4  = (const float*)d_in[1];
    const float* bias        = (const float*)d_in[2];
    const float* input_scale = (const float*)d_in[3];
    const float* wscale      = (const float*)d_in[4];
    const float* ws2         = (const float*)d_in[5];
    float* out = (float*)d_out;
    unsigned short* xpack = (unsigned short*)d_ws;   // 512 KB

    prep_kernel<<<320, 256, 0, stream>>>(x, input_scale, bias, xpack, out);
    gemm_kernel<<<2048, 256, 0, stream>>>(weight_fp4, wscale, ws2, xpack, out);
}